// Round 1
// baseline (501.097 us; speedup 1.0000x reference)
//
#include <hip/hip_runtime.h>

#define Bc 4
#define Sc 2048
#define Ec 1024
#define Hc 16
#define Dc 64
#define BSc 8192  // B*S

typedef short bf16x8 __attribute__((ext_vector_type(8)));
typedef float f32x4 __attribute__((ext_vector_type(4)));
typedef unsigned short u16;

__device__ __forceinline__ u16 f2bf(float f){
  unsigned u = __builtin_bit_cast(unsigned, f);
  u += 0x7FFFu + ((u >> 16) & 1u);
  return (u16)(u >> 16);
}
__device__ __forceinline__ float bf2f(u16 h){
  unsigned u = ((unsigned)h) << 16;
  return __builtin_bit_cast(float, u);
}
__device__ __forceinline__ void gll16(const void* g, void* l){
  __builtin_amdgcn_global_load_lds((const __attribute__((address_space(1))) void*)g,
                                   (__attribute__((address_space(3))) void*)l, 16, 0, 0);
}

// ---- split x (fp32 -> bf16 hi + bf16 lo) ----
__global__ void split_x_kernel(const float* __restrict__ x, u16* __restrict__ hi,
                               u16* __restrict__ lo, int n){
  int i = (blockIdx.x * 256 + threadIdx.x) * 4;
  if (i >= n) return;
  float4 v = *(const float4*)(x + i);
  u16 h0=f2bf(v.x), h1=f2bf(v.y), h2=f2bf(v.z), h3=f2bf(v.w);
  *(ushort4*)(hi+i) = make_ushort4(h0,h1,h2,h3);
  *(ushort4*)(lo+i) = make_ushort4(f2bf(v.x-bf2f(h0)), f2bf(v.y-bf2f(h1)),
                                   f2bf(v.z-bf2f(h2)), f2bf(v.w-bf2f(h3)));
}

// ---- transpose + split weights: W[k][n] fp32 -> Wt_hi[n][k], Wt_lo[n][k] bf16 ----
__global__ void wsplit_kernel(const float* __restrict__ w0, const float* __restrict__ w1,
                              const float* __restrict__ w2, const float* __restrict__ w3,
                              u16* __restrict__ hi, u16* __restrict__ lo){
  const float* w = blockIdx.z==0 ? w0 : blockIdx.z==1 ? w1 : blockIdx.z==2 ? w2 : w3;
  u16* ho = hi + (size_t)blockIdx.z * Ec * Ec;
  u16* lg = lo + (size_t)blockIdx.z * Ec * Ec;
  __shared__ float t[32][33];
  int k0 = blockIdx.y * 32, n0 = blockIdx.x * 32;
  int tx = threadIdx.x & 31, ty = threadIdx.x >> 5;
  for (int i = 0; i < 4; ++i){
    int k = ty + i*8;
    t[k][tx] = w[(size_t)(k0+k)*Ec + n0 + tx];
  }
  __syncthreads();
  for (int i = 0; i < 4; ++i){
    int nn = ty + i*8;
    float v = t[tx][nn];
    u16 h = f2bf(v);
    size_t idx = (size_t)(n0+nn)*Ec + k0 + tx;
    ho[idx] = h;
    lg[idx] = f2bf(v - bf2f(h));
  }
}

// ---- GEMM: C[M][N] = A[M][K] @ Bt[N][K]^T, 3-pass bf16 hi/lo split ----
// MODE 0: Q -> bf16 head layout [bh][s][d], scaled by 0.125
// MODE 1: K -> bf16 head layout [bh][s][d]
// MODE 2: V -> bf16 transposed  [bh][d][s]
// MODE 3: fp32 row-major out (final projection)
template<int MODE>
__global__ __launch_bounds__(256, 2)
void gemm_bt(const u16* __restrict__ Ahi, const u16* __restrict__ Alo,
             const u16* __restrict__ Bhi, const u16* __restrict__ Blo,
             const float* __restrict__ bias, void* __restrict__ outp)
{
  constexpr int K = Ec;
  __shared__ alignas(16) u16 As[128*32];
  __shared__ alignas(16) u16 Bs[128*32];
  const int tid = threadIdx.x, lane = tid & 63, w = tid >> 6;
  const int wr = w >> 1, wc = w & 1;
  const int m0 = blockIdx.y * 128, n0 = blockIdx.x * 128;
  const int l15 = lane & 15, kslot = lane >> 4;
  const f32x4 fz = {0.f,0.f,0.f,0.f};
  f32x4 acc[4][4];
  for (int i=0;i<4;++i) for (int j=0;j<4;++j) acc[i][j] = fz;

  const u16* Aps[3] = {Ahi, Ahi, Alo};
  const u16* Bps[3] = {Bhi, Blo, Bhi};
  const int srow = lane >> 2, sslot = lane & 3;

  for (int pass = 0; pass < 3; ++pass){
    const u16* Ap = Aps[pass];
    const u16* Bp = Bps[pass];
    for (int k0 = 0; k0 < K; k0 += 32){
      __syncthreads();
      for (int i = 0; i < 2; ++i){
        int c = w*2 + i;
        int row = c*16 + srow;
        int sw = (row ^ (row >> 2)) & 3;               // slot swizzle, 2 bits
        gll16(Ap + (size_t)(m0+row)*K + k0 + ((sslot ^ sw) << 3), As + c*512);
        gll16(Bp + (size_t)(n0+row)*K + k0 + ((sslot ^ sw) << 3), Bs + c*512);
      }
      __syncthreads();
      bf16x8 af[4], bfr[4];
      for (int mi = 0; mi < 4; ++mi){
        int row = wr*64 + mi*16 + l15;
        int sw = (row ^ (row >> 2)) & 3;
        af[mi] = *(const bf16x8*)(As + row*32 + ((kslot ^ sw) << 3));
      }
      for (int ni = 0; ni < 4; ++ni){
        int row = wc*64 + ni*16 + l15;
        int sw = (row ^ (row >> 2)) & 3;
        bfr[ni] = *(const bf16x8*)(Bs + row*32 + ((kslot ^ sw) << 3));
      }
      for (int mi = 0; mi < 4; ++mi)
        for (int ni = 0; ni < 4; ++ni)
          acc[mi][ni] = __builtin_amdgcn_mfma_f32_16x16x32_bf16(af[mi], bfr[ni], acc[mi][ni], 0, 0, 0);
    }
  }

  for (int mi = 0; mi < 4; ++mi){
    for (int ni = 0; ni < 4; ++ni){
      int col = n0 + wc*64 + ni*16 + l15;
      int row0 = m0 + wr*64 + mi*16 + kslot*4;
      float bi = bias[col];
      if (MODE == 2){
        int bb = row0 >> 11, s0 = row0 & 2047;
        int hh = col >> 6, dd = col & 63;
        ushort4 pk = make_ushort4(f2bf(acc[mi][ni][0]+bi), f2bf(acc[mi][ni][1]+bi),
                                  f2bf(acc[mi][ni][2]+bi), f2bf(acc[mi][ni][3]+bi));
        *(ushort4*)((u16*)outp + ((size_t)(bb*Hc+hh)*Dc + dd)*Sc + s0) = pk;
      } else {
        for (int j = 0; j < 4; ++j){
          float v = acc[mi][ni][j] + bi;
          int row = row0 + j;
          if (MODE == 0 || MODE == 1){
            float vv = (MODE == 0) ? v * 0.125f : v;
            int bb = row >> 11, ss = row & 2047;
            int hh = col >> 6, dd = col & 63;
            ((u16*)outp)[((size_t)(bb*Hc+hh)*Sc + ss)*Dc + dd] = f2bf(vv);
          } else {
            ((float*)outp)[(size_t)row*Ec + col] = v;
          }
        }
      }
    }
  }
}

// ---- flash attention: 4 waves x 16 q-rows, KV tiles of 64 ----
__global__ __launch_bounds__(256, 2)
void attn_kernel(const u16* __restrict__ qb, const u16* __restrict__ kb,
                 const u16* __restrict__ vt, const int* __restrict__ mask,
                 u16* __restrict__ ohi, u16* __restrict__ olo)
{
  __shared__ alignas(16) u16 Ks[64*64];
  __shared__ alignas(16) u16 Vs[64*64];
  __shared__ alignas(16) u16 Ps[4][16*64];
  __shared__ float mb[64];
  const int tid = threadIdx.x, lane = tid & 63, w = tid >> 6;
  const int l15 = lane & 15, kslot = lane >> 4;
  const int bh = blockIdx.y, b = bh >> 4, h = bh & 15;
  const int q0 = blockIdx.x*64 + w*16;
  const u16* Q  = qb + (size_t)bh*Sc*Dc;
  const u16* Kg = kb + (size_t)bh*Sc*Dc;
  const u16* Vg = vt + (size_t)bh*Dc*Sc;

  bf16x8 qf[2];
  {
    int row = q0 + l15;
    qf[0] = *(const bf16x8*)(Q + (size_t)row*Dc + kslot*8);
    qf[1] = *(const bf16x8*)(Q + (size_t)row*Dc + 32 + kslot*8);
  }
  const f32x4 fz = {0.f,0.f,0.f,0.f};
  f32x4 o[4] = {fz,fz,fz,fz};
  float m[4] = {-3e38f,-3e38f,-3e38f,-3e38f};
  float l[4] = {0.f,0.f,0.f,0.f};
  u16* P = &Ps[w][0];

  for (int t0 = 0; t0 < Sc; t0 += 64){
    __syncthreads();
    for (int i = 0; i < 2; ++i){
      int c = w*2 + i;
      int row = c*8 + (lane >> 3);
      int slot = lane & 7;
      int sw = row & 7;                                // slot swizzle, 3 bits
      gll16(Kg + (size_t)(t0+row)*Dc + ((slot ^ sw) << 3), Ks + c*512);
      gll16(Vg + (size_t)row*Sc + t0 + ((slot ^ sw) << 3), Vs + c*512);
    }
    if (tid < 64) mb[tid] = mask[b*Sc + t0 + tid] ? 0.f : -3e38f;
    __syncthreads();

    // S = Q @ K^T   (scale folded into Q)
    f32x4 sc[4];
    for (int cb = 0; cb < 4; ++cb){
      sc[cb] = fz;
      int trow = cb*16 + l15;
      int sw = trow & 7;
      sc[cb] = __builtin_amdgcn_mfma_f32_16x16x32_bf16(
          qf[0], *(const bf16x8*)(Ks + trow*64 + (((kslot    ) ^ sw) << 3)), sc[cb], 0,0,0);
      sc[cb] = __builtin_amdgcn_mfma_f32_16x16x32_bf16(
          qf[1], *(const bf16x8*)(Ks + trow*64 + (((4 + kslot) ^ sw) << 3)), sc[cb], 0,0,0);
    }
    // mask + online softmax (rows live in lanes: row = kslot*4+r, col = cb*16+l15)
    float tmax[4] = {-3e38f,-3e38f,-3e38f,-3e38f};
    for (int cb = 0; cb < 4; ++cb){
      float bi = mb[cb*16 + l15];
      for (int r = 0; r < 4; ++r){
        sc[cb][r] += bi;
        tmax[r] = fmaxf(tmax[r], sc[cb][r]);
      }
    }
    for (int off = 1; off < 16; off <<= 1)
      for (int r = 0; r < 4; ++r)
        tmax[r] = fmaxf(tmax[r], __shfl_xor(tmax[r], off, 64));
    float alpha[4], rsum[4] = {0.f,0.f,0.f,0.f};
    for (int r = 0; r < 4; ++r){
      float mn = fmaxf(m[r], tmax[r]);
      alpha[r] = __expf(m[r] - mn);
      m[r] = mn;
    }
    for (int cb = 0; cb < 4; ++cb){
      int col = cb*16 + l15;
      for (int r = 0; r < 4; ++r){
        float p = __expf(sc[cb][r] - m[r]);
        rsum[r] += p;
        int pr = kslot*4 + r;
        P[pr*64 + (col ^ ((pr & 7) << 3))] = f2bf(p);
      }
    }
    for (int off = 1; off < 16; off <<= 1)
      for (int r = 0; r < 4; ++r)
        rsum[r] += __shfl_xor(rsum[r], off, 64);
    for (int r = 0; r < 4; ++r) l[r] = l[r]*alpha[r] + rsum[r];
    for (int db = 0; db < 4; ++db)
      for (int r = 0; r < 4; ++r)
        o[db][r] *= alpha[r];
    asm volatile("s_waitcnt lgkmcnt(0)" ::: "memory");  // P writes visible before reads
    // O += P @ V  (Vs holds V^T: rows=d, cols=t)
    for (int kt = 0; kt < 2; ++kt){
      int pr = l15;
      int swp = pr & 7;
      bf16x8 pf = *(const bf16x8*)(P + pr*64 + (((kt*4 + kslot) ^ swp) << 3));
      for (int db = 0; db < 4; ++db){
        int vr = db*16 + l15;
        int swv = vr & 7;
        bf16x8 vf = *(const bf16x8*)(Vs + vr*64 + (((kt*4 + kslot) ^ swv) << 3));
        o[db] = __builtin_amdgcn_mfma_f32_16x16x32_bf16(pf, vf, o[db], 0, 0, 0);
      }
    }
  }
  // epilogue: divide by l, split hi/lo for the final split-GEMM
  for (int db = 0; db < 4; ++db){
    for (int r = 0; r < 4; ++r){
      int ss = q0 + kslot*4 + r;
      float v = o[db][r] / l[r];
      size_t idx = ((size_t)(b*Sc + ss))*Ec + h*64 + db*16 + l15;
      u16 hh = f2bf(v);
      ohi[idx] = hh;
      olo[idx] = f2bf(v - bf2f(hh));
    }
  }
}

extern "C" void kernel_launch(void* const* d_in, const int* in_sizes, int n_in,
                              void* d_out, int out_size, void* d_ws, size_t ws_size,
                              hipStream_t stream) {
  const float* x  = (const float*)d_in[0];
  const int* mask = (const int*)d_in[1];
  const float* Wq = (const float*)d_in[2];
  const float* bq = (const float*)d_in[3];
  const float* Wk = (const float*)d_in[4];
  const float* bk = (const float*)d_in[5];
  const float* Wv = (const float*)d_in[6];
  const float* bv = (const float*)d_in[7];
  const float* Wo = (const float*)d_in[8];
  const float* bo = (const float*)d_in[9];
  float* out = (float*)d_out;

  // workspace layout (u16 units); total 67,108,864 u16 = 134.2 MB
  u16* ws   = (u16*)d_ws;
  u16* x_hi = ws;
  u16* x_lo = x_hi + (size_t)BSc*Ec;
  u16* w_hi = x_lo + (size_t)BSc*Ec;      // 4 transposed weight matrices
  u16* w_lo = w_hi + (size_t)4*Ec*Ec;
  u16* q_bf = w_lo + (size_t)4*Ec*Ec;     // [bh][s][d], pre-scaled by 1/8
  u16* k_bf = q_bf + (size_t)BSc*Ec;      // [bh][s][d]
  u16* v_t  = k_bf + (size_t)BSc*Ec;      // [bh][d][s]
  u16* o_hi = v_t  + (size_t)BSc*Ec;      // [b*S+s][e]
  u16* o_lo = o_hi + (size_t)BSc*Ec;

  split_x_kernel<<<BSc*Ec/1024, 256, 0, stream>>>(x, x_hi, x_lo, BSc*Ec);
  wsplit_kernel<<<dim3(32,32,4), 256, 0, stream>>>(Wq, Wk, Wv, Wo, w_hi, w_lo);

  const size_t WSZ = (size_t)Ec*Ec;
  gemm_bt<0><<<dim3(8,64), 256, 0, stream>>>(x_hi, x_lo, w_hi+0*WSZ, w_lo+0*WSZ, bq, q_bf);
  gemm_bt<1><<<dim3(8,64), 256, 0, stream>>>(x_hi, x_lo, w_hi+1*WSZ, w_lo+1*WSZ, bk, k_bf);
  gemm_bt<2><<<dim3(8,64), 256, 0, stream>>>(x_hi, x_lo, w_hi+2*WSZ, w_lo+2*WSZ, bv, v_t);

  attn_kernel<<<dim3(32,64), 256, 0, stream>>>(q_bf, k_bf, v_t, mask, o_hi, o_lo);

  gemm_bt<3><<<dim3(8,64), 256, 0, stream>>>(o_hi, o_lo, w_hi+3*WSZ, w_lo+3*WSZ, bo, out);
}

// Round 2
// 263.872 us; speedup vs baseline: 1.8990x; 1.8990x over previous
//
#include <hip/hip_runtime.h>

#define Bc 4
#define Sc 2048
#define Ec 1024
#define Hc 16
#define Dc 64
#define BSc 8192  // B*S
#define KVB 128

typedef short bf16x8 __attribute__((ext_vector_type(8)));
typedef float f32x4 __attribute__((ext_vector_type(4)));
typedef unsigned short u16;

__device__ __forceinline__ u16 f2bf(float f){
  unsigned u = __builtin_bit_cast(unsigned, f);
  u += 0x7FFFu + ((u >> 16) & 1u);
  return (u16)(u >> 16);
}
__device__ __forceinline__ void gll16(const void* g, void* l){
  __builtin_amdgcn_global_load_lds((const __attribute__((address_space(1))) void*)g,
                                   (__attribute__((address_space(3))) void*)l, 16, 0, 0);
}
__device__ __forceinline__ float exp2_raw(float x){
  float r;
  asm("v_exp_f32 %0, %1" : "=v"(r) : "v"(x));
  return r;
}

// ---- x fp32 -> bf16 ----
__global__ void cvt_x_kernel(const float* __restrict__ x, u16* __restrict__ xb, int n){
  int i = (blockIdx.x * 256 + threadIdx.x) * 4;
  if (i >= n) return;
  float4 v = *(const float4*)(x + i);
  *(ushort4*)(xb+i) = make_ushort4(f2bf(v.x), f2bf(v.y), f2bf(v.z), f2bf(v.w));
}

// ---- transpose + convert weights: W[k][n] fp32 -> Wt[n][k] bf16 ----
__global__ void wt_kernel(const float* __restrict__ w0, const float* __restrict__ w1,
                          const float* __restrict__ w2, const float* __restrict__ w3,
                          u16* __restrict__ wt){
  const float* w = blockIdx.z==0 ? w0 : blockIdx.z==1 ? w1 : blockIdx.z==2 ? w2 : w3;
  u16* ho = wt + (size_t)blockIdx.z * Ec * Ec;
  __shared__ float t[32][33];
  int k0 = blockIdx.y * 32, n0 = blockIdx.x * 32;
  int tx = threadIdx.x & 31, ty = threadIdx.x >> 5;
  for (int i = 0; i < 4; ++i){
    int k = ty + i*8;
    t[k][tx] = w[(size_t)(k0+k)*Ec + n0 + tx];
  }
  __syncthreads();
  for (int i = 0; i < 4; ++i){
    int nn = ty + i*8;
    ho[(size_t)(n0+nn)*Ec + k0 + tx] = f2bf(t[tx][nn]);
  }
}

// ---- GEMM: C[M][N] = A[M][K] @ Bt[N][K]^T, single-pass bf16 ----
// MODE 0: Q -> bf16 head layout [bh][s][d], scaled by 0.125*log2(e)
// MODE 1: K -> bf16 head layout [bh][s][d]
// MODE 2: V -> bf16 transposed  [bh][d][s]
// MODE 3: fp32 row-major out (final projection)
template<int MODE>
__global__ __launch_bounds__(256, 2)
void gemm_bt(const u16* __restrict__ A, const u16* __restrict__ Bt,
             const float* __restrict__ bias, void* __restrict__ outp)
{
  constexpr int K = Ec;
  __shared__ alignas(16) u16 As[128*32];
  __shared__ alignas(16) u16 Bs[128*32];
  const int tid = threadIdx.x, lane = tid & 63, w = tid >> 6;
  const int wr = w >> 1, wc = w & 1;
  const int m0 = blockIdx.y * 128, n0 = blockIdx.x * 128;
  const int l15 = lane & 15, kslot = lane >> 4;
  const f32x4 fz = {0.f,0.f,0.f,0.f};
  f32x4 acc[4][4];
  for (int i=0;i<4;++i) for (int j=0;j<4;++j) acc[i][j] = fz;

  const int srow = lane >> 2, sslot = lane & 3;

  for (int k0 = 0; k0 < K; k0 += 32){
    __syncthreads();
    for (int i = 0; i < 2; ++i){
      int c = w*2 + i;
      int row = c*16 + srow;
      int sw = (row ^ (row >> 2)) & 3;               // slot swizzle, 2 bits
      gll16(A  + (size_t)(m0+row)*K + k0 + ((sslot ^ sw) << 3), As + c*512);
      gll16(Bt + (size_t)(n0+row)*K + k0 + ((sslot ^ sw) << 3), Bs + c*512);
    }
    __syncthreads();
    bf16x8 af[4], bfr[4];
    for (int mi = 0; mi < 4; ++mi){
      int row = wr*64 + mi*16 + l15;
      int sw = (row ^ (row >> 2)) & 3;
      af[mi] = *(const bf16x8*)(As + row*32 + ((kslot ^ sw) << 3));
    }
    for (int ni = 0; ni < 4; ++ni){
      int row = wc*64 + ni*16 + l15;
      int sw = (row ^ (row >> 2)) & 3;
      bfr[ni] = *(const bf16x8*)(Bs + row*32 + ((kslot ^ sw) << 3));
    }
    for (int mi = 0; mi < 4; ++mi)
      for (int ni = 0; ni < 4; ++ni)
        acc[mi][ni] = __builtin_amdgcn_mfma_f32_16x16x32_bf16(af[mi], bfr[ni], acc[mi][ni], 0, 0, 0);
  }

  for (int mi = 0; mi < 4; ++mi){
    for (int ni = 0; ni < 4; ++ni){
      int col = n0 + wc*64 + ni*16 + l15;
      int row0 = m0 + wr*64 + mi*16 + kslot*4;
      float bi = bias[col];
      if (MODE == 2){
        int bb = row0 >> 11, s0 = row0 & 2047;
        int hh = col >> 6, dd = col & 63;
        ushort4 pk = make_ushort4(f2bf(acc[mi][ni][0]+bi), f2bf(acc[mi][ni][1]+bi),
                                  f2bf(acc[mi][ni][2]+bi), f2bf(acc[mi][ni][3]+bi));
        *(ushort4*)((u16*)outp + ((size_t)(bb*Hc+hh)*Dc + dd)*Sc + s0) = pk;
      } else {
        for (int j = 0; j < 4; ++j){
          float v = acc[mi][ni][j] + bi;
          int row = row0 + j;
          if (MODE == 0 || MODE == 1){
            float vv = (MODE == 0) ? v * 0.18033688f : v;   // 0.125 * log2(e)
            int bb = row >> 11, ss = row & 2047;
            int hh = col >> 6, dd = col & 63;
            ((u16*)outp)[((size_t)(bb*Hc+hh)*Sc + ss)*Dc + dd] = f2bf(vv);
          } else {
            ((float*)outp)[(size_t)row*Ec + col] = v;
          }
        }
      }
    }
  }
}

// ---- flash attention: 4 waves x 16 q-rows, KV tiles of 128, base-2 softmax ----
__global__ __launch_bounds__(256, 3)
void attn_kernel(const u16* __restrict__ qb, const u16* __restrict__ kb,
                 const u16* __restrict__ vt, const int* __restrict__ mask,
                 u16* __restrict__ ob)
{
  __shared__ alignas(16) u16 Ks[KVB*Dc];      // [t][d]  128B rows, slot-swizzled
  __shared__ alignas(16) u16 Vs[Dc*KVB];      // [d][t]  256B rows, slot-swizzled
  __shared__ alignas(16) u16 Ps[4][16*KVB];   // per-wave P [q][t], slot-swizzled
  const int tid = threadIdx.x, lane = tid & 63, w = tid >> 6;
  const int l15 = lane & 15, kslot = lane >> 4;
  // XCD-affinity remap: xcd = f&7 streams bh = (f&7)*8 + (f>>8), q-blocks in order
  const int f = blockIdx.x + (blockIdx.y << 5);
  const int bh = ((f & 7) << 3) | (f >> 8);
  const int qblk = (f >> 3) & 31;
  const int b = bh >> 4, h = bh & 15;
  const int q0 = qblk*64 + w*16;

  const u16* Q  = qb + (size_t)bh*Sc*Dc;
  const u16* Kt = kb + (size_t)bh*Sc*Dc;
  const u16* Vt = vt + (size_t)bh*Dc*Sc;
  const int* mp = mask + b*Sc;

  // per-lane global staging offsets (u16 units), loop-invariant
  int koff[4], voff[4];
#pragma unroll
  for (int i = 0; i < 4; ++i){
    int c = w*4 + i;
    int kr = c*8 + (lane >> 3);
    koff[i] = kr*Dc + (((lane & 7) ^ (kr & 7)) << 3);
    int vr = c*4 + (lane >> 4);
    voff[i] = vr*Sc + (((lane & 15) ^ (vr & 15)) << 3);
  }
  // LDS read/write byte offsets, loop-invariant (XOR-composable)
  const char* Ksb = (const char*)Ks;
  const char* Vsb = (const char*)Vs;
  char* Pb = (char*)&Ps[w][0];
  int krb[8], vrb[4], pwb[4];
#pragma unroll
  for (int cb = 0; cb < 8; ++cb){
    int tr = cb*16 + l15;
    krb[cb] = tr*128 + ((kslot ^ (tr & 7)) << 4);
  }
#pragma unroll
  for (int db = 0; db < 4; ++db){
    int vr = db*16 + l15;
    vrb[db] = vr*256 + ((kslot ^ (vr & 15)) << 4);
  }
#pragma unroll
  for (int r = 0; r < 4; ++r){
    int pr = kslot*4 + r;
    pwb[r] = pr*256 + (((l15 >> 3) ^ pr) << 4) + (l15 & 7)*2;
  }
  const int prb = l15*256 + ((kslot ^ l15) << 4);

  bf16x8 qf0, qf1, onesb;
  {
    const u16* qrow = Q + (size_t)(q0 + l15)*Dc + kslot*8;
    qf0 = *(const bf16x8*)(qrow);
    qf1 = *(const bf16x8*)(qrow + 32);
  }
#pragma unroll
  for (int j = 0; j < 8; ++j) onesb[j] = (short)0x3F80;  // bf16 1.0

  const f32x4 fz = {0.f,0.f,0.f,0.f};
  f32x4 o[4] = {fz,fz,fz,fz};
  float m[4] = {-3e38f,-3e38f,-3e38f,-3e38f};
  float l[4] = {0.f,0.f,0.f,0.f};

  for (int t0 = 0; t0 < Sc; t0 += KVB){
    __syncthreads();
#pragma unroll
    for (int i = 0; i < 4; ++i){
      int c = w*4 + i;
      gll16(Kt + koff[i], Ks + c*512);
      gll16(Vt + voff[i], Vs + c*512);
    }
    int m0v = mp[lane], m1v = mp[64 + lane];
    Kt += KVB*Dc; Vt += KVB; mp += KVB;
    __syncthreads();

    // S = Q @ K^T (log2-domain: scale*log2e folded into Q)
    f32x4 sc[8];
#pragma unroll
    for (int cb = 0; cb < 8; ++cb){
      bf16x8 k0 = *(const bf16x8*)(Ksb + krb[cb]);
      bf16x8 k1 = *(const bf16x8*)(Ksb + (krb[cb] ^ 64));
      sc[cb] = __builtin_amdgcn_mfma_f32_16x16x32_bf16(qf0, k0, fz, 0,0,0);
      sc[cb] = __builtin_amdgcn_mfma_f32_16x16x32_bf16(qf1, k1, sc[cb], 0,0,0);
    }
    if (!__all(m0v && m1v)){                 // mask slow path (cold for all-ones mask)
      float b0 = m0v ? 0.f : -3e38f;
      float b1 = m1v ? 0.f : -3e38f;
#pragma unroll
      for (int cb = 0; cb < 8; ++cb){
        float bi = __shfl(cb < 4 ? b0 : b1, ((cb & 3) << 4) | l15, 64);
#pragma unroll
        for (int r = 0; r < 4; ++r) sc[cb][r] += bi;
      }
    }
    // row max: rows live as (kslot*4+r) in lanes, cols cb*16+l15
    float tmax[4];
#pragma unroll
    for (int r = 0; r < 4; ++r){
      float a0 = fmaxf(sc[0][r], sc[1][r]), a1 = fmaxf(sc[2][r], sc[3][r]);
      float a2 = fmaxf(sc[4][r], sc[5][r]), a3 = fmaxf(sc[6][r], sc[7][r]);
      tmax[r] = fmaxf(fmaxf(a0, a1), fmaxf(a2, a3));
    }
#pragma unroll
    for (int off = 1; off < 16; off <<= 1)
#pragma unroll
      for (int r = 0; r < 4; ++r)
        tmax[r] = fmaxf(tmax[r], __shfl_xor(tmax[r], off, 64));
    float al[4];
#pragma unroll
    for (int r = 0; r < 4; ++r){
      float mn = fmaxf(m[r], tmax[r]);
      al[r] = exp2_raw(m[r] - mn);
      m[r] = mn;
    }
    // P = exp2(S - m), packed to bf16 via cvt_pk, swizzled LDS store
#pragma unroll
    for (int cb = 0; cb < 8; cb += 2){
#pragma unroll
      for (int r = 0; r < 4; ++r){
        float p0 = exp2_raw(sc[cb][r] - m[r]);
        float p1 = exp2_raw(sc[cb+1][r] - m[r]);
        unsigned pk;
        asm("v_cvt_pk_bf16_f32 %0, %1, %2" : "=v"(pk) : "v"(p0), "v"(p1));
        *(u16*)(Pb + (pwb[r] ^ (cb << 5)))     = (u16)pk;
        *(u16*)(Pb + (pwb[r] ^ ((cb+1) << 5))) = (u16)(pk >> 16);
      }
    }
#pragma unroll
    for (int db = 0; db < 4; ++db)
#pragma unroll
      for (int r = 0; r < 4; ++r)
        o[db][r] *= al[r];
    asm volatile("s_waitcnt lgkmcnt(0)" ::: "memory");
    // O += P @ V^T; row-sum l via ones-vector MFMA (no shfl reduce)
    f32x4 accl = fz;
#pragma unroll
    for (int kt = 0; kt < 4; ++kt){
      bf16x8 pf = *(const bf16x8*)(Pb + (prb ^ (kt << 6)));
      accl = __builtin_amdgcn_mfma_f32_16x16x32_bf16(pf, onesb, accl, 0,0,0);
#pragma unroll
      for (int db = 0; db < 4; ++db){
        bf16x8 vf = *(const bf16x8*)(Vsb + (vrb[db] ^ (kt << 6)));
        o[db] = __builtin_amdgcn_mfma_f32_16x16x32_bf16(pf, vf, o[db], 0,0,0);
      }
    }
#pragma unroll
    for (int r = 0; r < 4; ++r) l[r] = l[r]*al[r] + accl[r];
  }
  // epilogue: normalize, write bf16 [b*S+s][E]
#pragma unroll
  for (int r = 0; r < 4; ++r){
    float inv = __builtin_amdgcn_rcpf(l[r]);
    int ss = q0 + kslot*4 + r;
    u16* orow = ob + ((size_t)(b*Sc + ss))*Ec + h*Dc + l15;
#pragma unroll
    for (int db = 0; db < 4; ++db)
      orow[db*16] = f2bf(o[db][r] * inv);
  }
}

extern "C" void kernel_launch(void* const* d_in, const int* in_sizes, int n_in,
                              void* d_out, int out_size, void* d_ws, size_t ws_size,
                              hipStream_t stream) {
  const float* x  = (const float*)d_in[0];
  const int* mask = (const int*)d_in[1];
  const float* Wq = (const float*)d_in[2];
  const float* bq = (const float*)d_in[3];
  const float* Wk = (const float*)d_in[4];
  const float* bk = (const float*)d_in[5];
  const float* Wv = (const float*)d_in[6];
  const float* bv = (const float*)d_in[7];
  const float* Wo = (const float*)d_in[8];
  const float* bo = (const float*)d_in[9];
  float* out = (float*)d_out;

  // workspace layout (u16 units)
  u16* ws   = (u16*)d_ws;
  u16* x_bf = ws;                          // [b*S+s][e]
  u16* w_t  = x_bf + (size_t)BSc*Ec;       // 4 transposed weight matrices [n][k]
  u16* q_bf = w_t  + (size_t)4*Ec*Ec;      // [bh][s][d], pre-scaled by 0.125*log2e
  u16* k_bf = q_bf + (size_t)BSc*Ec;       // [bh][s][d]
  u16* v_t  = k_bf + (size_t)BSc*Ec;       // [bh][d][s]
  u16* o_bf = v_t  + (size_t)BSc*Ec;       // [b*S+s][e]

  cvt_x_kernel<<<BSc*Ec/1024, 256, 0, stream>>>(x, x_bf, BSc*Ec);
  wt_kernel<<<dim3(32,32,4), 256, 0, stream>>>(Wq, Wk, Wv, Wo, w_t);

  const size_t WSZ = (size_t)Ec*Ec;
  gemm_bt<0><<<dim3(8,64), 256, 0, stream>>>(x_bf, w_t+0*WSZ, bq, q_bf);
  gemm_bt<1><<<dim3(8,64), 256, 0, stream>>>(x_bf, w_t+1*WSZ, bk, k_bf);
  gemm_bt<2><<<dim3(8,64), 256, 0, stream>>>(x_bf, w_t+2*WSZ, bv, v_t);

  attn_kernel<<<dim3(32,64), 256, 0, stream>>>(q_bf, k_bf, v_t, mask, o_bf);

  gemm_bt<3><<<dim3(8,64), 256, 0, stream>>>(o_bf, w_t+3*WSZ, bo, out);
}

// Round 4
// 224.658 us; speedup vs baseline: 2.2305x; 1.1745x over previous
//
#include <hip/hip_runtime.h>

#define Bc 4
#define Sc 2048
#define Ec 1024
#define Hc 16
#define Dc 64
#define BSc 8192  // B*S
#define KVB 64

typedef short bf16x8 __attribute__((ext_vector_type(8)));
typedef float f32x4 __attribute__((ext_vector_type(4)));
typedef unsigned short u16;
typedef unsigned long long u64;

__device__ __forceinline__ u16 f2bf(float f){
  unsigned u = __builtin_bit_cast(unsigned, f);
  u += 0x7FFFu + ((u >> 16) & 1u);
  return (u16)(u >> 16);
}
__device__ __forceinline__ void gll16(const void* g, void* l){
  __builtin_amdgcn_global_load_lds((const __attribute__((address_space(1))) void*)g,
                                   (__attribute__((address_space(3))) void*)l, 16, 0, 0);
}
// exp2: TRANS op. Builtin path lets the compiler handle the TRANS->VALU hazard;
// asm fallback embeds s_nop 1 as explicit wait states.
__device__ __forceinline__ float exp2_s(float x){
#if __has_builtin(__builtin_amdgcn_exp2f)
  return __builtin_amdgcn_exp2f(x);
#else
  float r;
  asm volatile("v_exp_f32 %0, %1\n\ts_nop 1" : "=v"(r) : "v"(x));
  return r;
#endif
}
// cvt_pk result feeds MFMA operands directly: embed wait states for the
// VALU-write -> MFMA-read hazard the recognizer can't see through inline asm.
__device__ __forceinline__ unsigned cvtpk(float a, float b){
  unsigned r;
  asm volatile("v_cvt_pk_bf16_f32 %0, %1, %2\n\ts_nop 1" : "=v"(r) : "v"(a), "v"(b));
  return r;
}

// ---- x fp32 -> bf16 ----
__global__ void cvt_x_kernel(const float* __restrict__ x, u16* __restrict__ xb, int n){
  int i = (blockIdx.x * 256 + threadIdx.x) * 4;
  if (i >= n) return;
  float4 v = *(const float4*)(x + i);
  *(ushort4*)(xb+i) = make_ushort4(f2bf(v.x), f2bf(v.y), f2bf(v.z), f2bf(v.w));
}

// ---- transpose + convert weights: W[k][n] fp32 -> Wt[n][k] bf16 ----
__global__ void wt_kernel(const float* __restrict__ w0, const float* __restrict__ w1,
                          const float* __restrict__ w2, const float* __restrict__ w3,
                          u16* __restrict__ wt){
  const float* w = blockIdx.z==0 ? w0 : blockIdx.z==1 ? w1 : blockIdx.z==2 ? w2 : w3;
  u16* ho = wt + (size_t)blockIdx.z * Ec * Ec;
  __shared__ float t[32][33];
  int k0 = blockIdx.y * 32, n0 = blockIdx.x * 32;
  int tx = threadIdx.x & 31, ty = threadIdx.x >> 5;
  for (int i = 0; i < 4; ++i){
    int k = ty + i*8;
    t[k][tx] = w[(size_t)(k0+k)*Ec + n0 + tx];
  }
  __syncthreads();
  for (int i = 0; i < 4; ++i){
    int nn = ty + i*8;
    ho[(size_t)(n0+nn)*Ec + k0 + tx] = f2bf(t[tx][nn]);
  }
}

// ---- GEMM: C[M][N] = A[M][K] @ Bt[N][K]^T, single-pass bf16 ----
template<int MODE>
__global__ __launch_bounds__(256, 2)
void gemm_bt(const u16* __restrict__ A, const u16* __restrict__ Bt,
             const float* __restrict__ bias, void* __restrict__ outp)
{
  constexpr int K = Ec;
  __shared__ alignas(16) u16 As[128*32];
  __shared__ alignas(16) u16 Bs[128*32];
  const int tid = threadIdx.x, lane = tid & 63, w = tid >> 6;
  const int wr = w >> 1, wc = w & 1;
  const int m0 = blockIdx.y * 128, n0 = blockIdx.x * 128;
  const int l15 = lane & 15, kslot = lane >> 4;
  const f32x4 fz = {0.f,0.f,0.f,0.f};
  f32x4 acc[4][4];
  for (int i=0;i<4;++i) for (int j=0;j<4;++j) acc[i][j] = fz;

  const int srow = lane >> 2, sslot = lane & 3;

  for (int k0 = 0; k0 < K; k0 += 32){
    __syncthreads();
    for (int i = 0; i < 2; ++i){
      int c = w*2 + i;
      int row = c*16 + srow;
      int sw = (row ^ (row >> 2)) & 3;
      gll16(A  + (size_t)(m0+row)*K + k0 + ((sslot ^ sw) << 3), As + c*512);
      gll16(Bt + (size_t)(n0+row)*K + k0 + ((sslot ^ sw) << 3), Bs + c*512);
    }
    __syncthreads();
    bf16x8 af[4], bfr[4];
    for (int mi = 0; mi < 4; ++mi){
      int row = wr*64 + mi*16 + l15;
      int sw = (row ^ (row >> 2)) & 3;
      af[mi] = *(const bf16x8*)(As + row*32 + ((kslot ^ sw) << 3));
    }
    for (int ni = 0; ni < 4; ++ni){
      int row = wc*64 + ni*16 + l15;
      int sw = (row ^ (row >> 2)) & 3;
      bfr[ni] = *(const bf16x8*)(Bs + row*32 + ((kslot ^ sw) << 3));
    }
    for (int mi = 0; mi < 4; ++mi)
      for (int ni = 0; ni < 4; ++ni)
        acc[mi][ni] = __builtin_amdgcn_mfma_f32_16x16x32_bf16(af[mi], bfr[ni], acc[mi][ni], 0, 0, 0);
  }

  for (int mi = 0; mi < 4; ++mi){
    for (int ni = 0; ni < 4; ++ni){
      int col = n0 + wc*64 + ni*16 + l15;
      int row0 = m0 + wr*64 + mi*16 + kslot*4;
      float bi = bias[col];
      if (MODE == 2){
        int bb = row0 >> 11, s0 = row0 & 2047;
        int hh = col >> 6, dd = col & 63;
        ushort4 pk = make_ushort4(f2bf(acc[mi][ni][0]+bi), f2bf(acc[mi][ni][1]+bi),
                                  f2bf(acc[mi][ni][2]+bi), f2bf(acc[mi][ni][3]+bi));
        *(ushort4*)((u16*)outp + ((size_t)(bb*Hc+hh)*Dc + dd)*Sc + s0) = pk;
      } else {
        for (int j = 0; j < 4; ++j){
          float v = acc[mi][ni][j] + bi;
          int row = row0 + j;
          if (MODE == 0 || MODE == 1){
            float vv = (MODE == 0) ? v * 0.18033688f : v;   // 0.125 * log2(e)
            int bb = row >> 11, ss = row & 2047;
            int hh = col >> 6, dd = col & 63;
            ((u16*)outp)[((size_t)(bb*Hc+hh)*Sc + ss)*Dc + dd] = f2bf(vv);
          } else {
            ((float*)outp)[(size_t)row*Ec + col] = v;
          }
        }
      }
    }
  }
}

// ---- flash attention: 4 waves x 32 q-rows each, KV tiles of 64, dbuf staging,
//      swapped QK^T (scores lane-local per q-col), P kept in registers via
//      consistent kv-permutation of the PV operands, O^T accumulation ----
__global__ __launch_bounds__(256, 2)
void attn_kernel(const u16* __restrict__ qb, const u16* __restrict__ kb,
                 const u16* __restrict__ vt, const int* __restrict__ mask,
                 u16* __restrict__ ob)
{
  __shared__ alignas(16) u16 Ks[2][KVB*Dc];   // [t][d] 128B rows, slot-swizzled
  __shared__ alignas(16) u16 Vs[2][Dc*KVB];   // [d][t] 128B rows, slot-swizzled
  const int tid = threadIdx.x, lane = tid & 63, w = tid >> 6;
  const int l15 = lane & 15, ks = lane >> 4;
  // XCD-affinity remap: 1024 blocks -> xcd*128 + orig/8 (bijective)
  const int wg = ((blockIdx.x & 7) << 7) | (blockIdx.x >> 3);
  const int bh = wg >> 4, qblk = wg & 15;
  const int b = bh >> 4, h = bh & 15;
  const int q0 = qblk*128 + w*32;

  const u16* Q  = qb + (size_t)bh*Sc*Dc;
  const u16* Kg = kb + (size_t)bh*Sc*Dc;
  const u16* Vg = vt + (size_t)bh*Dc*Sc;
  const int* mpb = mask + b*Sc;

  // staging offsets (pre-swizzled global source, linear LDS dest)
  int koff[2], voff[2];
#pragma unroll
  for (int i = 0; i < 2; ++i){
    int S = (w*2+i)*64 + lane;
    int row = S >> 3, s = S & 7;
    koff[i] = row*Dc + ((s ^ (row & 7)) << 3);
    voff[i] = row*Sc + ((s ^ (row & 7)) << 3);
  }
  const int Xl = (l15 & 7) << 4;

  // Q fragments (B-operand: col=l15 -> q, k=ks*8+j -> d)
  bf16x8 qf[2][2];
#pragma unroll
  for (int qa = 0; qa < 2; ++qa)
#pragma unroll
    for (int kd = 0; kd < 2; ++kd)
      qf[qa][kd] = *(const bf16x8*)(Q + (size_t)(q0 + qa*16 + l15)*Dc + kd*32 + ks*8);

  bf16x8 onesb;
#pragma unroll
  for (int j = 0; j < 8; ++j) onesb[j] = (short)0x3F80;  // bf16 1.0

  const f32x4 fz = {0.f,0.f,0.f,0.f};
  f32x4 o[2][4];
#pragma unroll
  for (int qa = 0; qa < 2; ++qa)
#pragma unroll
    for (int db = 0; db < 4; ++db) o[qa][db] = fz;
  float m[2] = {-3e38f, -3e38f}, runl[2] = {0.f, 0.f};

  // prologue: stage tile 0 -> buf 0
#pragma unroll
  for (int i = 0; i < 2; ++i){
    gll16(Kg + koff[i], &Ks[0][(w*2+i)*512]);
    gll16(Vg + voff[i], &Vs[0][(w*2+i)*512]);
  }

  const int NT = Sc / KVB;
  int cur = 0;
  for (int t = 0; t < NT; ++t){
    asm volatile("s_waitcnt vmcnt(0)" ::: "memory");  // belt: DMA landed
    __syncthreads();                                  // buf[cur] ready for all waves
    if (t + 1 < NT){                       // prefetch next tile into buf^1
      const u16* kg = Kg + (size_t)(t+1)*(KVB*Dc);
      const u16* vg = Vg + (size_t)(t+1)*KVB;
#pragma unroll
      for (int i = 0; i < 2; ++i){
        gll16(kg + koff[i], &Ks[cur^1][(w*2+i)*512]);
        gll16(vg + voff[i], &Vs[cur^1][(w*2+i)*512]);
      }
    }
    const char* Ksb = (const char*)&Ks[cur][0];
    const char* Vsb = (const char*)&Vs[cur][0];

    // S^T = K @ Q^T : lane holds kv = nb*16 + ks*4 + r, q = qa*16 + l15
    f32x4 sc[4][2];
#pragma unroll
    for (int nb = 0; nb < 4; ++nb){
      bf16x8 kf0 = *(const bf16x8*)(Ksb + nb*2048 + l15*128 + (((0*4+ks) << 4) ^ Xl));
      bf16x8 kf1 = *(const bf16x8*)(Ksb + nb*2048 + l15*128 + (((1*4+ks) << 4) ^ Xl));
#pragma unroll
      for (int qa = 0; qa < 2; ++qa){
        sc[nb][qa] = __builtin_amdgcn_mfma_f32_16x16x32_bf16(kf0, qf[qa][0], fz, 0,0,0);
        sc[nb][qa] = __builtin_amdgcn_mfma_f32_16x16x32_bf16(kf1, qf[qa][1], sc[nb][qa], 0,0,0);
      }
    }
    // key-padding mask (cold path for all-ones mask)
    const int* mp = mpb + t*KVB;
    int mv = mp[lane];
    if (!__all(mv != 0)){
#pragma unroll
      for (int nb = 0; nb < 4; ++nb)
#pragma unroll
        for (int r = 0; r < 4; ++r){
          float bi = mp[nb*16 + ks*4 + r] ? 0.f : -3e38f;
          sc[nb][0][r] += bi;
          sc[nb][1][r] += bi;
        }
    }
    // per-q-col max: in-lane over 16 values + reduce over ks groups
    float tmax[2];
#pragma unroll
    for (int qa = 0; qa < 2; ++qa){
      f32x4 mx4;
#pragma unroll
      for (int r = 0; r < 4; ++r)
        mx4[r] = fmaxf(fmaxf(sc[0][qa][r], sc[1][qa][r]),
                       fmaxf(sc[2][qa][r], sc[3][qa][r]));
      float tv = fmaxf(fmaxf(mx4[0], mx4[1]), fmaxf(mx4[2], mx4[3]));
      tv = fmaxf(tv, __shfl_xor(tv, 16, 64));
      tv = fmaxf(tv, __shfl_xor(tv, 32, 64));
      tmax[qa] = tv;
    }
    // defer-max: rescale only when the running max grows past THR=8 (log2 domain)
    bool need = (t == 0) ||
                !__all((tmax[0] <= m[0] + 8.f) && (tmax[1] <= m[1] + 8.f));
    if (need){
#pragma unroll
      for (int qa = 0; qa < 2; ++qa){
        float nm = fmaxf(m[qa], tmax[qa]);
        float al = exp2_s(m[qa] - nm);
        m[qa] = nm;
        runl[qa] *= al;
#pragma unroll
        for (int db = 0; db < 4; ++db)
#pragma unroll
          for (int r = 0; r < 4; ++r)
            o[qa][db][r] *= al;
      }
    }
    // P = exp2(S - m) in place
#pragma unroll
    for (int nb = 0; nb < 4; ++nb)
#pragma unroll
      for (int qa = 0; qa < 2; ++qa)
#pragma unroll
        for (int r = 0; r < 4; ++r)
          sc[nb][qa][r] = exp2_s(sc[nb][qa][r] - m[qa]);

    // PV with kv-permutation pi(kt,ks,j) = kt*32 + 16*(j>>2) + ks*4 + (j&3)
    // applied to BOTH operands: P stays in registers; O^T = V^T @ P
    f32x4 accl[2] = {fz, fz};
#pragma unroll
    for (int kt = 0; kt < 2; ++kt){
      bf16x8 pb[2];
#pragma unroll
      for (int qa = 0; qa < 2; ++qa){
        union { bf16x8 v; unsigned u[4]; } pu;
        pu.u[0] = cvtpk(sc[2*kt  ][qa][0], sc[2*kt  ][qa][1]);
        pu.u[1] = cvtpk(sc[2*kt  ][qa][2], sc[2*kt  ][qa][3]);
        pu.u[2] = cvtpk(sc[2*kt+1][qa][0], sc[2*kt+1][qa][1]);
        pu.u[3] = cvtpk(sc[2*kt+1][qa][2], sc[2*kt+1][qa][3]);
        pb[qa] = pu.v;
      }
      accl[0] = __builtin_amdgcn_mfma_f32_16x16x32_bf16(onesb, pb[0], accl[0], 0,0,0);
      accl[1] = __builtin_amdgcn_mfma_f32_16x16x32_bf16(onesb, pb[1], accl[1], 0,0,0);
#pragma unroll
      for (int db = 0; db < 4; ++db){
        union { bf16x8 v; u64 q[2]; } vu;
        const int g0 = kt*4 + (ks >> 1);
        const int base = db*2048 + l15*128 + (ks & 1)*8;
        vu.q[0] = *(const u64*)(Vsb + base + (((g0    ) << 4) ^ Xl));
        vu.q[1] = *(const u64*)(Vsb + base + (((g0 + 2) << 4) ^ Xl));
#pragma unroll
        for (int qa = 0; qa < 2; ++qa)
          o[qa][db] = __builtin_amdgcn_mfma_f32_16x16x32_bf16(vu.v, pb[qa], o[qa][db], 0,0,0);
      }
    }
    runl[0] += accl[0][0];
    runl[1] += accl[1][0];
    cur ^= 1;
  }
  // epilogue: O[q][d], q = qa*16+l15 (same layout as l), d = db*16 + ks*4 + r
#pragma unroll
  for (int qa = 0; qa < 2; ++qa){
    float inv = __builtin_amdgcn_rcpf(fmaxf(runl[qa], 1e-35f));
    u16* orow = ob + ((size_t)(b*Sc + q0 + qa*16 + l15))*Ec + h*Dc + ks*4;
#pragma unroll
    for (int db = 0; db < 4; ++db){
      ushort4 pk = make_ushort4(f2bf(o[qa][db][0]*inv), f2bf(o[qa][db][1]*inv),
                                f2bf(o[qa][db][2]*inv), f2bf(o[qa][db][3]*inv));
      *(ushort4*)(orow + db*16) = pk;
    }
  }
}

extern "C" void kernel_launch(void* const* d_in, const int* in_sizes, int n_in,
                              void* d_out, int out_size, void* d_ws, size_t ws_size,
                              hipStream_t stream) {
  const float* x  = (const float*)d_in[0];
  const int* mask = (const int*)d_in[1];
  const float* Wq = (const float*)d_in[2];
  const float* bq = (const float*)d_in[3];
  const float* Wk = (const float*)d_in[4];
  const float* bk = (const float*)d_in[5];
  const float* Wv = (const float*)d_in[6];
  const float* bv = (const float*)d_in[7];
  const float* Wo = (const float*)d_in[8];
  const float* bo = (const float*)d_in[9];
  float* out = (float*)d_out;

  u16* ws   = (u16*)d_ws;
  u16* x_bf = ws;                          // [b*S+s][e]
  u16* w_t  = x_bf + (size_t)BSc*Ec;       // 4 transposed weight matrices [n][k]
  u16* q_bf = w_t  + (size_t)4*Ec*Ec;      // [bh][s][d], pre-scaled by 0.125*log2e
  u16* k_bf = q_bf + (size_t)BSc*Ec;       // [bh][s][d]
  u16* v_t  = k_bf + (size_t)BSc*Ec;       // [bh][d][s]
  u16* o_bf = v_t  + (size_t)BSc*Ec;       // [b*S+s][e]

  cvt_x_kernel<<<BSc*Ec/1024, 256, 0, stream>>>(x, x_bf, BSc*Ec);
  wt_kernel<<<dim3(32,32,4), 256, 0, stream>>>(Wq, Wk, Wv, Wo, w_t);

  const size_t WSZ = (size_t)Ec*Ec;
  gemm_bt<0><<<dim3(8,64), 256, 0, stream>>>(x_bf, w_t+0*WSZ, bq, q_bf);
  gemm_bt<1><<<dim3(8,64), 256, 0, stream>>>(x_bf, w_t+1*WSZ, bk, k_bf);
  gemm_bt<2><<<dim3(8,64), 256, 0, stream>>>(x_bf, w_t+2*WSZ, bv, v_t);

  attn_kernel<<<dim3(1024), 256, 0, stream>>>(q_bf, k_bf, v_t, mask, o_bf);

  gemm_bt<3><<<dim3(8,64), 256, 0, stream>>>(o_bf, w_t+3*WSZ, bo, out);
}

// Round 6
// 204.330 us; speedup vs baseline: 2.4524x; 1.0995x over previous
//
#include <hip/hip_runtime.h>

#define Bc 4
#define Sc 2048
#define Ec 1024
#define Hc 16
#define Dc 64
#define BSc 8192  // B*S
#define KVB 64

typedef short bf16x8 __attribute__((ext_vector_type(8)));
typedef float f32x4 __attribute__((ext_vector_type(4)));
typedef unsigned short u16;
typedef unsigned long long u64;

__device__ __forceinline__ u16 f2bf(float f){
  unsigned u = __builtin_bit_cast(unsigned, f);
  u += 0x7FFFu + ((u >> 16) & 1u);
  return (u16)(u >> 16);
}
__device__ __forceinline__ void gll16(const void* g, void* l){
  __builtin_amdgcn_global_load_lds((const __attribute__((address_space(1))) void*)g,
                                   (__attribute__((address_space(3))) void*)l, 16, 0, 0);
}
// exp2: TRANS op. Builtin path lets the compiler handle the TRANS->VALU hazard.
__device__ __forceinline__ float exp2_s(float x){
#if __has_builtin(__builtin_amdgcn_exp2f)
  return __builtin_amdgcn_exp2f(x);
#else
  float r;
  asm volatile("v_exp_f32 %0, %1\n\ts_nop 1" : "=v"(r) : "v"(x));
  return r;
#endif
}
// cvt_pk result feeds MFMA operands directly: keep explicit wait states.
__device__ __forceinline__ unsigned cvtpk(float a, float b){
  unsigned r;
  asm volatile("v_cvt_pk_bf16_f32 %0, %1, %2\n\ts_nop 1" : "=v"(r) : "v"(a), "v"(b));
  return r;
}

// ---- x fp32 -> bf16 ----
__global__ void cvt_x_kernel(const float* __restrict__ x, u16* __restrict__ xb, int n){
  int i = (blockIdx.x * 256 + threadIdx.x) * 4;
  if (i >= n) return;
  float4 v = *(const float4*)(x + i);
  *(ushort4*)(xb+i) = make_ushort4(f2bf(v.x), f2bf(v.y), f2bf(v.z), f2bf(v.w));
}

// ---- transpose + convert weights: W[k][n] fp32 -> Wt[n][k] bf16 ----
__global__ void wt_kernel(const float* __restrict__ w0, const float* __restrict__ w1,
                          const float* __restrict__ w2, const float* __restrict__ w3,
                          u16* __restrict__ wt){
  const float* w = blockIdx.z==0 ? w0 : blockIdx.z==1 ? w1 : blockIdx.z==2 ? w2 : w3;
  u16* ho = wt + (size_t)blockIdx.z * Ec * Ec;
  __shared__ float t[32][33];
  int k0 = blockIdx.y * 32, n0 = blockIdx.x * 32;
  int tx = threadIdx.x & 31, ty = threadIdx.x >> 5;
  for (int i = 0; i < 4; ++i){
    int k = ty + i*8;
    t[k][tx] = w[(size_t)(k0+k)*Ec + n0 + tx];
  }
  __syncthreads();
  for (int i = 0; i < 4; ++i){
    int nn = ty + i*8;
    ho[(size_t)(n0+nn)*Ec + k0 + tx] = f2bf(t[tx][nn]);
  }
}

// ---- fused QKV GEMM: C[M][3072] = A[M][K] @ [Wq;Wk;Wv]^T, m97 structure ----
// which = n block / 1024: 0 -> Q [bh][s][d] scaled by 0.125*log2(e)
//                         1 -> K [bh][s][d]
//                         2 -> V^T [bh][d][s]  (linear s, round-4-proven layout)
__global__ __launch_bounds__(256, 2)
void gemm_qkv(const u16* __restrict__ A, const u16* __restrict__ Wt,
              const float* __restrict__ bq, const float* __restrict__ bk,
              const float* __restrict__ bv,
              u16* __restrict__ qout, u16* __restrict__ kout, u16* __restrict__ vout)
{
  constexpr int K = Ec;
  __shared__ alignas(16) u16 As[128*32];
  __shared__ alignas(16) u16 Bs[128*32];
  const int tid = threadIdx.x, lane = tid & 63, w = tid >> 6;
  const int wr = w >> 1, wc = w & 1;
  const int m0 = blockIdx.y * 128;
  const int n0g = blockIdx.x * 128;
  const int which = n0g >> 10;
  const int n0 = n0g & 1023;
  const u16* Bt = Wt + (size_t)which * Ec * Ec;
  const float* bias = which == 0 ? bq : which == 1 ? bk : bv;
  const int l15 = lane & 15, kslot = lane >> 4;
  const f32x4 fz = {0.f,0.f,0.f,0.f};
  f32x4 acc[4][4];
  for (int i=0;i<4;++i) for (int j=0;j<4;++j) acc[i][j] = fz;

  const int srow = lane >> 2, sslot = lane & 3;

  for (int k0 = 0; k0 < K; k0 += 32){
    __syncthreads();
    for (int i = 0; i < 2; ++i){
      int c = w*2 + i;
      int row = c*16 + srow;
      int sw = (row ^ (row >> 2)) & 3;
      gll16(A  + (size_t)(m0+row)*K + k0 + ((sslot ^ sw) << 3), As + c*512);
      gll16(Bt + (size_t)(n0+row)*K + k0 + ((sslot ^ sw) << 3), Bs + c*512);
    }
    __syncthreads();
    bf16x8 af[4], bfr[4];
    for (int mi = 0; mi < 4; ++mi){
      int row = wr*64 + mi*16 + l15;
      int sw = (row ^ (row >> 2)) & 3;
      af[mi] = *(const bf16x8*)(As + row*32 + ((kslot ^ sw) << 3));
    }
    for (int ni = 0; ni < 4; ++ni){
      int row = wc*64 + ni*16 + l15;
      int sw = (row ^ (row >> 2)) & 3;
      bfr[ni] = *(const bf16x8*)(Bs + row*32 + ((kslot ^ sw) << 3));
    }
    for (int mi = 0; mi < 4; ++mi)
      for (int ni = 0; ni < 4; ++ni)
        acc[mi][ni] = __builtin_amdgcn_mfma_f32_16x16x32_bf16(af[mi], bfr[ni], acc[mi][ni], 0, 0, 0);
  }

  for (int mi = 0; mi < 4; ++mi){
    for (int ni = 0; ni < 4; ++ni){
      int col = n0 + wc*64 + ni*16 + l15;           // 0..1023 within this matrix
      int row0 = m0 + wr*64 + mi*16 + kslot*4;
      float bi = bias[col];
      if (which == 2){
        // V^T, linear s (round-4-proven)
        int bb = row0 >> 11, s0 = row0 & 2047;
        int hh = col >> 6, dd = col & 63;
        ushort4 pk = make_ushort4(f2bf(acc[mi][ni][0]+bi), f2bf(acc[mi][ni][1]+bi),
                                  f2bf(acc[mi][ni][2]+bi), f2bf(acc[mi][ni][3]+bi));
        *(ushort4*)(vout + ((size_t)(bb*Hc+hh)*Dc + dd)*Sc + s0) = pk;
      } else {
        u16* dst = which == 0 ? qout : kout;
        for (int j = 0; j < 4; ++j){
          float v = acc[mi][ni][j] + bi;
          int row = row0 + j;
          float vv = (which == 0) ? v * 0.18033688f : v;   // 0.125 * log2(e)
          int bb = row >> 11, ss = row & 2047;
          int hh = col >> 6, dd = col & 63;
          dst[((size_t)(bb*Hc+hh)*Sc + ss)*Dc + dd] = f2bf(vv);
        }
      }
    }
  }
}

// ---- output projection GEMM: fp32 out ----
__global__ __launch_bounds__(256, 2)
void gemm_out(const u16* __restrict__ A, const u16* __restrict__ Bt,
              const float* __restrict__ bias, float* __restrict__ outp)
{
  constexpr int K = Ec;
  __shared__ alignas(16) u16 As[128*32];
  __shared__ alignas(16) u16 Bs[128*32];
  const int tid = threadIdx.x, lane = tid & 63, w = tid >> 6;
  const int wr = w >> 1, wc = w & 1;
  const int m0 = blockIdx.y * 128, n0 = blockIdx.x * 128;
  const int l15 = lane & 15, kslot = lane >> 4;
  const f32x4 fz = {0.f,0.f,0.f,0.f};
  f32x4 acc[4][4];
  for (int i=0;i<4;++i) for (int j=0;j<4;++j) acc[i][j] = fz;

  const int srow = lane >> 2, sslot = lane & 3;

  for (int k0 = 0; k0 < K; k0 += 32){
    __syncthreads();
    for (int i = 0; i < 2; ++i){
      int c = w*2 + i;
      int row = c*16 + srow;
      int sw = (row ^ (row >> 2)) & 3;
      gll16(A  + (size_t)(m0+row)*K + k0 + ((sslot ^ sw) << 3), As + c*512);
      gll16(Bt + (size_t)(n0+row)*K + k0 + ((sslot ^ sw) << 3), Bs + c*512);
    }
    __syncthreads();
    bf16x8 af[4], bfr[4];
    for (int mi = 0; mi < 4; ++mi){
      int row = wr*64 + mi*16 + l15;
      int sw = (row ^ (row >> 2)) & 3;
      af[mi] = *(const bf16x8*)(As + row*32 + ((kslot ^ sw) << 3));
    }
    for (int ni = 0; ni < 4; ++ni){
      int row = wc*64 + ni*16 + l15;
      int sw = (row ^ (row >> 2)) & 3;
      bfr[ni] = *(const bf16x8*)(Bs + row*32 + ((kslot ^ sw) << 3));
    }
    for (int mi = 0; mi < 4; ++mi)
      for (int ni = 0; ni < 4; ++ni)
        acc[mi][ni] = __builtin_amdgcn_mfma_f32_16x16x32_bf16(af[mi], bfr[ni], acc[mi][ni], 0, 0, 0);
  }

  for (int mi = 0; mi < 4; ++mi){
    for (int ni = 0; ni < 4; ++ni){
      int col = n0 + wc*64 + ni*16 + l15;
      int row0 = m0 + wr*64 + mi*16 + kslot*4;
      float bi = bias[col];
      for (int j = 0; j < 4; ++j)
        outp[(size_t)(row0+j)*Ec + col] = acc[mi][ni][j] + bi;
    }
  }
}

// ---- flash attention: 4 waves x 32 q-rows, KV tiles of 64, dbuf staging,
//      swapped QK^T, P in registers (pi-permuted PV, round-4 two-u64 V read),
//      mask hoisted out of the loop, defer-max hot path without cross-lane ops ----
__global__ __launch_bounds__(256, 2)
void attn_kernel(const u16* __restrict__ qb, const u16* __restrict__ kb,
                 const u16* __restrict__ vt, const int* __restrict__ mask,
                 u16* __restrict__ ob)
{
  __shared__ alignas(16) u16 Ks[2][KVB*Dc];   // [t][d] 128B rows, slot-swizzled
  __shared__ alignas(16) u16 Vs[2][Dc*KVB];   // [d][t] 128B rows, slot-swizzled
  const int tid = threadIdx.x, lane = tid & 63, w = tid >> 6;
  const int l15 = lane & 15, ks = lane >> 4;
  // XCD-affinity remap: 1024 blocks -> xcd*128 + orig/8 (bijective)
  const int wg = ((blockIdx.x & 7) << 7) | (blockIdx.x >> 3);
  const int bh = wg >> 4, qblk = wg & 15;
  const int b = bh >> 4, h = bh & 15;
  const int q0 = qblk*128 + w*32;

  const u16* Q  = qb + (size_t)bh*Sc*Dc;
  const u16* Kg = kb + (size_t)bh*Sc*Dc;
  const u16* Vg = vt + (size_t)bh*Dc*Sc;
  const int* mpb = mask + b*Sc;

  // prologue mask scan: allvalid => zero mask work in the hot loop
  int nzl = 1;
  {
    const int4* mv4 = (const int4*)mpb;
#pragma unroll
    for (int i = 0; i < 8; ++i){
      int4 v = mv4[i*64 + lane];
      nzl &= (v.x && v.y && v.z && v.w) ? 1 : 0;
    }
  }
  const bool allvalid = __all(nzl);

  // staging offsets (pre-swizzled global source, linear LDS dest)
  int koff[2], voff[2];
#pragma unroll
  for (int i = 0; i < 2; ++i){
    int S = (w*2+i)*64 + lane;
    int row = S >> 3, s = S & 7;
    koff[i] = row*Dc + ((s ^ (row & 7)) << 3);
    voff[i] = row*Sc + ((s ^ (row & 7)) << 3);
  }
  const int Xl = (l15 & 7) << 4;

  // Q fragments (B-operand: col=l15 -> q, k=ks*8+j -> d)
  bf16x8 qf[2][2];
#pragma unroll
  for (int qa = 0; qa < 2; ++qa)
#pragma unroll
    for (int kd = 0; kd < 2; ++kd)
      qf[qa][kd] = *(const bf16x8*)(Q + (size_t)(q0 + qa*16 + l15)*Dc + kd*32 + ks*8);

  bf16x8 onesb;
#pragma unroll
  for (int j = 0; j < 8; ++j) onesb[j] = (short)0x3F80;  // bf16 1.0

  const f32x4 fz = {0.f,0.f,0.f,0.f};
  f32x4 o[2][4];
#pragma unroll
  for (int qa = 0; qa < 2; ++qa)
#pragma unroll
    for (int db = 0; db < 4; ++db) o[qa][db] = fz;
  float m[2] = {-3e38f, -3e38f}, runl[2] = {0.f, 0.f};

  // prologue: stage tile 0 -> buf 0
#pragma unroll
  for (int i = 0; i < 2; ++i){
    gll16(Kg + koff[i], &Ks[0][(w*2+i)*512]);
    gll16(Vg + voff[i], &Vs[0][(w*2+i)*512]);
  }

  const int NT = Sc / KVB;
  int cur = 0;
  for (int t = 0; t < NT; ++t){
    asm volatile("s_waitcnt vmcnt(0)" ::: "memory");  // DMA landed
    __syncthreads();                                  // buf[cur] ready for all waves
    if (t + 1 < NT){                       // prefetch next tile into buf^1
      const u16* kg = Kg + (size_t)(t+1)*(KVB*Dc);
      const u16* vg = Vg + (size_t)(t+1)*KVB;
#pragma unroll
      for (int i = 0; i < 2; ++i){
        gll16(kg + koff[i], &Ks[cur^1][(w*2+i)*512]);
        gll16(vg + voff[i], &Vs[cur^1][(w*2+i)*512]);
      }
    }
    const char* Ksb = (const char*)&Ks[cur][0];
    const char* Vsb = (const char*)&Vs[cur][0];

    // S^T = K @ Q^T : lane holds kv = nb*16 + ks*4 + r, q = qa*16 + l15
    f32x4 sc[4][2];
#pragma unroll
    for (int nb = 0; nb < 4; ++nb){
      bf16x8 kf0 = *(const bf16x8*)(Ksb + nb*2048 + l15*128 + (((0*4+ks) << 4) ^ Xl));
      bf16x8 kf1 = *(const bf16x8*)(Ksb + nb*2048 + l15*128 + (((1*4+ks) << 4) ^ Xl));
#pragma unroll
      for (int qa = 0; qa < 2; ++qa){
        sc[nb][qa] = __builtin_amdgcn_mfma_f32_16x16x32_bf16(kf0, qf[qa][0], fz, 0,0,0);
        sc[nb][qa] = __builtin_amdgcn_mfma_f32_16x16x32_bf16(kf1, qf[qa][1], sc[nb][qa], 0,0,0);
      }
    }
    // key-padding mask (cold for all-valid mask; per-tile scalar loads otherwise)
    if (!allvalid){
      const int* mp = mpb + t*KVB;
#pragma unroll
      for (int nb = 0; nb < 4; ++nb)
#pragma unroll
        for (int r = 0; r < 4; ++r){
          float bi = mp[nb*16 + ks*4 + r] ? 0.f : -3e38f;
          sc[nb][0][r] += bi;
          sc[nb][1][r] += bi;
        }
    }
    // in-lane partial max per qa (no cross-lane in the hot path)
    float pmax[2];
#pragma unroll
    for (int qa = 0; qa < 2; ++qa){
      f32x4 mx4;
#pragma unroll
      for (int r = 0; r < 4; ++r)
        mx4[r] = fmaxf(fmaxf(sc[0][qa][r], sc[1][qa][r]),
                       fmaxf(sc[2][qa][r], sc[3][qa][r]));
      pmax[qa] = fmaxf(fmaxf(mx4[0], mx4[1]), fmaxf(mx4[2], mx4[3]));
    }
    // defer-max: rescale only if some lane's partial max exceeds m+8 (log2 dom.)
    int ok = (t > 0) && (pmax[0] <= m[0] + 8.f) && (pmax[1] <= m[1] + 8.f);
    if (!__all(ok)){
#pragma unroll
      for (int qa = 0; qa < 2; ++qa){
        float tv = pmax[qa];
        tv = fmaxf(tv, __shfl_xor(tv, 16, 64));
        tv = fmaxf(tv, __shfl_xor(tv, 32, 64));
        float nm = fmaxf(m[qa], tv);
        float al = exp2_s(m[qa] - nm);
        m[qa] = nm;
        runl[qa] *= al;
#pragma unroll
        for (int db = 0; db < 4; ++db)
#pragma unroll
          for (int r = 0; r < 4; ++r)
            o[qa][db][r] *= al;
      }
    }
    // P = exp2(S - m) in place
#pragma unroll
    for (int nb = 0; nb < 4; ++nb)
#pragma unroll
      for (int qa = 0; qa < 2; ++qa)
#pragma unroll
        for (int r = 0; r < 4; ++r)
          sc[nb][qa][r] = exp2_s(sc[nb][qa][r] - m[qa]);

    // PV: pi(kt,ks,j) = kt*32 + 16*(j>>2) + ks*4 + (j&3) on BOTH operands.
    // P stays in registers; V fragment assembled from two u64 LDS reads (round-4).
    f32x4 accl[2] = {fz, fz};
#pragma unroll
    for (int kt = 0; kt < 2; ++kt){
      bf16x8 pb[2];
#pragma unroll
      for (int qa = 0; qa < 2; ++qa){
        union { bf16x8 v; unsigned u[4]; } pu;
        pu.u[0] = cvtpk(sc[2*kt  ][qa][0], sc[2*kt  ][qa][1]);
        pu.u[1] = cvtpk(sc[2*kt  ][qa][2], sc[2*kt  ][qa][3]);
        pu.u[2] = cvtpk(sc[2*kt+1][qa][0], sc[2*kt+1][qa][1]);
        pu.u[3] = cvtpk(sc[2*kt+1][qa][2], sc[2*kt+1][qa][3]);
        pb[qa] = pu.v;
      }
      accl[0] = __builtin_amdgcn_mfma_f32_16x16x32_bf16(onesb, pb[0], accl[0], 0,0,0);
      accl[1] = __builtin_amdgcn_mfma_f32_16x16x32_bf16(onesb, pb[1], accl[1], 0,0,0);
#pragma unroll
      for (int db = 0; db < 4; ++db){
        union { bf16x8 v; u64 q[2]; } vu;
        const int g0 = kt*4 + (ks >> 1);
        const int base = db*2048 + l15*128 + (ks & 1)*8;
        vu.q[0] = *(const u64*)(Vsb + base + (((g0    ) << 4) ^ Xl));
        vu.q[1] = *(const u64*)(Vsb + base + (((g0 + 2) << 4) ^ Xl));
#pragma unroll
        for (int qa = 0; qa < 2; ++qa)
          o[qa][db] = __builtin_amdgcn_mfma_f32_16x16x32_bf16(vu.v, pb[qa], o[qa][db], 0,0,0);
      }
    }
    runl[0] += accl[0][0];
    runl[1] += accl[1][0];
    cur ^= 1;
  }
  // epilogue: O[q][d], q = qa*16+l15 (same layout as l), d = db*16 + ks*4 + r
#pragma unroll
  for (int qa = 0; qa < 2; ++qa){
    float inv = __builtin_amdgcn_rcpf(fmaxf(runl[qa], 1e-35f));
    u16* orow = ob + ((size_t)(b*Sc + q0 + qa*16 + l15))*Ec + h*Dc + ks*4;
#pragma unroll
    for (int db = 0; db < 4; ++db){
      ushort4 pk = make_ushort4(f2bf(o[qa][db][0]*inv), f2bf(o[qa][db][1]*inv),
                                f2bf(o[qa][db][2]*inv), f2bf(o[qa][db][3]*inv));
      *(ushort4*)(orow + db*16) = pk;
    }
  }
}

extern "C" void kernel_launch(void* const* d_in, const int* in_sizes, int n_in,
                              void* d_out, int out_size, void* d_ws, size_t ws_size,
                              hipStream_t stream) {
  const float* x  = (const float*)d_in[0];
  const int* mask = (const int*)d_in[1];
  const float* Wq = (const float*)d_in[2];
  const float* bq = (const float*)d_in[3];
  const float* Wk = (const float*)d_in[4];
  const float* bk = (const float*)d_in[5];
  const float* Wv = (const float*)d_in[6];
  const float* bv = (const float*)d_in[7];
  const float* Wo = (const float*)d_in[8];
  const float* bo = (const float*)d_in[9];
  float* out = (float*)d_out;

  u16* ws   = (u16*)d_ws;
  u16* x_bf = ws;                          // [b*S+s][e]
  u16* w_t  = x_bf + (size_t)BSc*Ec;       // 4 transposed weight matrices [n][k]
  u16* q_bf = w_t  + (size_t)4*Ec*Ec;      // [bh][s][d], pre-scaled by 0.125*log2e
  u16* k_bf = q_bf + (size_t)BSc*Ec;       // [bh][s][d]
  u16* v_t  = k_bf + (size_t)BSc*Ec;       // [bh][d][s]
  u16* o_bf = v_t  + (size_t)BSc*Ec;       // [b*S+s][e]

  cvt_x_kernel<<<BSc*Ec/1024, 256, 0, stream>>>(x, x_bf, BSc*Ec);
  wt_kernel<<<dim3(32,32,4), 256, 0, stream>>>(Wq, Wk, Wv, Wo, w_t);

  const size_t WSZ = (size_t)Ec*Ec;
  gemm_qkv<<<dim3(24,64), 256, 0, stream>>>(x_bf, w_t, bq, bk, bv, q_bf, k_bf, v_t);

  attn_kernel<<<dim3(1024), 256, 0, stream>>>(q_bf, k_bf, v_t, mask, o_bf);

  gemm_out<<<dim3(8,64), 256, 0, stream>>>(o_bf, w_t+3*WSZ, bo, out);
}